// Round 1
// baseline (133.399 us; speedup 1.0000x reference)
//
#include <hip/hip_runtime.h>

// PQ embedding gather:
//   out[t, m*32 + j] = centroids[m, item_codes[ids[t], m], j]
// B*S = 102400 tokens, M = 8 code bytes, SUB = 32 floats, 256 centroids/byte.
//   ids:        int32   [B*S]
//   item_codes: int32   [(N+1)*8]    (32 MB, random-row gather, zero reuse)
//   centroids:  float32 [8*256*32]   (256 KB, L1/L2 resident)
//   out:        float32 [B*S*256]    (105 MB streaming coalesced write)
//
// R7 restructure: barrier-free, LDS-free. One wave processes one token with
// all 64 lanes (lane l -> out floats t*256 + 4l .. +3; its code dword is
// codes[id*8 + (l>>3)], an 8-lane-broadcast read of the token's 32 B row).
// Each wave owns 8 consecutive tokens, staged as:
//   [8 NT code gathers][8 centroid gathers][8 1-KB stores]
// ALL loads are issued before ANY store, so vmcnt's in-order retirement
// never makes a load consumer wait on store-queue drain (the R6-era loop
// interleaved [8 loads][8 stores] per chunk, gating every chunk's loads on
// the previous chunk's store retirement under full write backpressure).
// Grid 3200 (was 800): 12.5 blocks/CU kills the 25% tail of 3.125 blocks/CU
// and lets VGPR-limited residency (not grid) set occupancy.
//   - nt *loads* on code rows kept (zero reuse; don't evict centroids).
//   - plain cached stores kept (R6: nt stores regressed).

typedef float f4 __attribute__((ext_vector_type(4)));

#define M_BYTES 8
#define SUB_DIM 32
#define EMB     (M_BYTES * SUB_DIM)   // 256 floats per token
#define TPW     8                     // tokens per wave
#define WAVES   4
#define TOK_PER_BLOCK (TPW * WAVES)   // 32
#define BLOCK   256

__global__ __launch_bounds__(BLOCK) void ItemCodeLayer_30253749633338_kernel(
    const int*   __restrict__ ids,    // [B*S]
    const int*   __restrict__ codes,  // [(N+1)*M]
    const float* __restrict__ cent,   // [M*256*SUB]
    float*       __restrict__ out,    // [B*S*EMB]
    int n_tokens)
{
    const int tid  = threadIdx.x;
    const int l    = tid & 63;
    const int wave = __builtin_amdgcn_readfirstlane(tid >> 6);  // SGPR wave id
    const int lm   = l >> 3;          // code byte handled by this lane group
    const int l4   = l * 4;           // = lm*SUB_DIM + (l&7)*4, lane's out offset

    const float* centBase = cent + (size_t)lm * 256 * SUB_DIM + (l & 7) * 4;

    const int t0 = blockIdx.x * TOK_PER_BLOCK + wave * TPW;

    if (t0 + TPW <= n_tokens) {
        // ---- fast path: no per-token guards, ids indices consecutive ----
        // Stage 1: 8 independent NT code gathers (random 32 B rows in 32 MB).
        int c[TPW];
        #pragma unroll
        for (int k = 0; k < TPW; ++k) {
            int id = ids[t0 + k];                       // wave-uniform -> s_load
            c[k] = __builtin_nontemporal_load(codes + (size_t)id * M_BYTES + lm);
        }
        // Stage 2: 8 centroid gathers (16 B/lane, 128 B row per 8-lane group).
        f4 v[TPW];
        #pragma unroll
        for (int k = 0; k < TPW; ++k)
            v[k] = *reinterpret_cast<const f4*>(centBase + (size_t)c[k] * SUB_DIM);
        // Stage 3: 8 streaming stores (64 lanes x 16 B = contiguous 1 KB).
        #pragma unroll
        for (int k = 0; k < TPW; ++k)
            *reinterpret_cast<f4*>(out + (size_t)(t0 + k) * EMB + l4) = v[k];
    } else if (t0 < n_tokens) {
        // ---- guarded tail (never taken at B*S = 102400 = 3200*32) ----
        #pragma unroll
        for (int k = 0; k < TPW; ++k) {
            int t = t0 + k;
            if (t < n_tokens) {
                int id  = ids[t];
                int cd  = codes[(size_t)id * M_BYTES + lm];
                f4 val  = *reinterpret_cast<const f4*>(centBase + (size_t)cd * SUB_DIM);
                *reinterpret_cast<f4*>(out + (size_t)t * EMB + l4) = val;
            }
        }
    }
}

extern "C" void kernel_launch(void* const* d_in, const int* in_sizes, int n_in,
                              void* d_out, int out_size, void* d_ws, size_t ws_size,
                              hipStream_t stream) {
    const int*   ids   = (const int*)  d_in[0];   // input_ids  [B*S] int32
    const int*   codes = (const int*)  d_in[1];   // item_codes [(N+1)*M] int32
    const float* cent  = (const float*)d_in[2];   // centroids  [M*256*SUB] float32
    float*       out   = (float*)      d_out;

    const int n_tokens = in_sizes[0];             // 102400 tokens
    const int grid = (n_tokens + TOK_PER_BLOCK - 1) / TOK_PER_BLOCK;   // 3200

    hipLaunchKernelGGL(ItemCodeLayer_30253749633338_kernel,
                       dim3(grid), dim3(BLOCK), 0, stream,
                       ids, codes, cent, out, n_tokens);
}